// Round 13
// baseline (135.105 us; speedup 1.0000x reference)
//
#include <hip/hip_runtime.h>
#include <math.h>

#define B_SZ 4
#define LQ_SZ 2048
#define C_SZ 256
#define NH_SZ 8
#define NL_SZ 4
#define NP_SZ 8
#define HD_SZ 32
#define LV_SZ 21760
#define NQ_SZ (B_SZ * LQ_SZ)   // 8192
#define MV_SZ (B_SZ * LV_SZ)   // 87040

typedef __attribute__((ext_vector_type(8))) short bf16x8;
typedef __attribute__((ext_vector_type(8))) unsigned short ushort8;
typedef __attribute__((ext_vector_type(4))) float f32x4;

__device__ __forceinline__ float bf2f(unsigned short u) {
  union { float f; unsigned v; } x;
  x.v = ((unsigned)u) << 16;
  return x.f;
}
__device__ __forceinline__ unsigned short f2bf(float f) {
  union { float f; unsigned v; } x;
  x.f = f;
  unsigned r = x.v + 0x7fffu + ((x.v >> 16) & 1u);
  return (unsigned short)(r >> 16);
}

// 8x f32 -> bf16x8 via v_cvt_pk_bf16_f32 (RNE, same as f2bf)
__device__ __forceinline__ bf16x8 cvt8(f32x4 a, f32x4 b) {
  union { unsigned u[4]; bf16x8 v; } r;
  asm("v_cvt_pk_bf16_f32 %0, %1, %2" : "=v"(r.u[0]) : "v"(a[0]), "v"(a[1]));
  asm("v_cvt_pk_bf16_f32 %0, %1, %2" : "=v"(r.u[1]) : "v"(a[2]), "v"(a[3]));
  asm("v_cvt_pk_bf16_f32 %0, %1, %2" : "=v"(r.u[2]) : "v"(b[0]), "v"(b[1]));
  asm("v_cvt_pk_bf16_f32 %0, %1, %2" : "=v"(r.u[3]) : "v"(b[2]), "v"(b[3]));
  return r.v;
}

// bank-permute: bijective on 0..7
__device__ __forceinline__ int swz(int x) {
  return ((x & 1) << 2) | ((x >> 1) & 3);
}

// ---------------------------------------------------------------------------
// One-shot weight prep (grid 1796 x 256).
// ---------------------------------------------------------------------------
__global__ void prep_weights(
    const float* __restrict__ Wv, const float* __restrict__ Wo,
    const float* __restrict__ W_off, const float* __restrict__ W_attn,
    const float* __restrict__ Wa1, const float* __restrict__ Wa2,
    const float* __restrict__ b_off, const float* __restrict__ b_attn,
    const float* __restrict__ ba1,
    unsigned short* __restrict__ wtv, unsigned short* __restrict__ wto,
    unsigned short* __restrict__ wcat, unsigned short* __restrict__ wa2t,
    float* __restrict__ bcat) {
  const int bid = blockIdx.x, t = threadIdx.x;
  if (bid < 256) {
    wtv[bid * 256 + t] = f2bf(Wv[t * 256 + bid]);
  } else if (bid < 512) {
    const int n = bid - 256;
    wto[n * 256 + t] = f2bf(Wo[t * 256 + n]);
  } else if (bid < 1536) {
    const int n = bid - 512;
    float v;
    if (n < 512) v = W_off[t * 512 + n];
    else if (n < 768) v = W_attn[t * 256 + (n - 512)];
    else if (n < 896) v = Wa1[t * 128 + (n - 768)];
    else v = 0.f;
    wcat[n * 256 + t] = f2bf(v);
  } else if (bid < 1792) {
    const int idx = (bid - 1536) * 256 + t;     // < 65536
    const int n = idx >> 7, k = idx & 127;
    wa2t[n * 128 + k] = f2bf(Wa2[k * 512 + n]);
  } else {
    const int idx = (bid - 1792) * 256 + t;     // < 1024
    float v;
    if (idx < 512) v = b_off[idx];
    else if (idx < 768) v = b_attn[idx - 512];
    else if (idx < 896) v = ba1[idx - 768];
    else v = 0.f;
    bcat[idx] = v;
  }
}

// ---------------------------------------------------------------------------
// Front-loaded single-barrier MFMA GEMM, v3 (BN = 64).
// C[M, n_total] = A[M, K_DIM] @ Wt^T + bias; Wt bf16 [n][K_DIM].
// Block = 512 thr = 8 waves; wave w owns rows bm+w*16 x 64 cols (bn0).
// LDS: 64 x K_DIM bf16 = 32 KB (K=256) / 16 KB (K=128) -> 3-5 blocks/CU so
// independent blocks de-phase and keep HBM busy.
// XCD map (flat 1D grid, NT n-tiles x MT m-tiles, MT%8==0):
//   xcd = bid%8, q = bid/8, n = q%NT, m = xcd + 8*(q/NT)
// -> all NT n-siblings of an m-tile land on the same XCD: A fetched once/L2.
// Staging: 8 threads/row, cl = i*8+qq, stored at cl^swz(row): uniform 8
// lanes per bank-quad per instr on write AND read -> conflict-free.
// MFMA operands swapped -> lane holds 4 consecutive C cols -> 8/16B stores.
// MODE: 0 = f32 out, 1 = bf16 out, 2 = proj (bn0<768 f32; else relu bf16
// -> aux[.,128]).
// ---------------------------------------------------------------------------
template <int MODE, int A_BF16, int K_DIM, int NT>
__global__ __launch_bounds__(512, 4) void gemm_wave(
    const void* __restrict__ Ain, const unsigned short* __restrict__ Wt,
    const float* __restrict__ bias, void* __restrict__ Cout,
    unsigned short* __restrict__ aux, int n_total) {
  constexpr int KSTEPS = K_DIM / 32;
  constexpr int CHUNKS = K_DIM / 8;          // 16-B chunks per B row
  __shared__ unsigned short Bs[64 * K_DIM];  // 32 KB (K=256) / 16 KB (K=128)
  const int bid = blockIdx.x;
  const int xcd = bid & 7;
  const int q = bid >> 3;
  const int bn0 = (q % NT) * 64;
  const long bm = (long)(xcd + 8 * (q / NT)) * 128;

  const int tid = threadIdx.x;
  const int lane = tid & 63;
  const int w = tid >> 6;
  const int rowc = lane & 15, rowg = lane >> 4;

  // ---- (a) B staging: 8 threads/row, interleaved chunks, swizzled ----
  {
    const int row = tid >> 3, qq = tid & 7;
    const unsigned short* src = Wt + (long)(bn0 + row) * K_DIM;
    char* dstrow = (char*)Bs + row * (K_DIM * 2);
    const int sz = swz(row);
#pragma unroll
    for (int i = 0; i < CHUNKS / 8; ++i) {
      const int cl = i * 8 + qq;
      ushort8 u = *(const ushort8*)(src + cl * 8);
      *(ushort8*)(dstrow + (cl ^ sz) * 16) = u;
    }
  }

  // ---- (b) A front-load into fragment registers ----
  bf16x8 afrag[KSTEPS];
  if constexpr (A_BF16) {
    const unsigned short* ap =
        (const unsigned short*)Ain + (bm + w * 16 + rowc) * (long)K_DIM +
        rowg * 8;
#pragma unroll
    for (int ks = 0; ks < KSTEPS; ++ks)
      afrag[ks] = *(const bf16x8*)(ap + ks * 32);
  } else {
    const float* ap =
        (const float*)Ain + (bm + w * 16 + rowc) * (long)K_DIM + rowg * 8;
#pragma unroll
    for (int ks = 0; ks < KSTEPS; ++ks) {
      f32x4 x0 = *(const f32x4*)(ap + ks * 32);
      f32x4 x1 = *(const f32x4*)(ap + ks * 32 + 4);
      afrag[ks] = cvt8(x0, x1);
    }
  }

  f32x4 acc[4];
#pragma unroll
  for (int n = 0; n < 4; ++n) acc[n] = (f32x4){0.f, 0.f, 0.f, 0.f};

  // ---- (c) the only barrier ----
  __syncthreads();

  // ---- (d) MFMA loop, swapped operands ----
#pragma unroll
  for (int ks = 0; ks < KSTEPS; ++ks) {
#pragma unroll
    for (int n = 0; n < 4; ++n) {
      const int col = n * 16 + rowc;
      const int cs = (ks * 4 + rowg) ^ swz(col);
      bf16x8 bf =
          *(const bf16x8*)((const char*)Bs + col * (K_DIM * 2) + cs * 16);
      acc[n] = __builtin_amdgcn_mfma_f32_16x16x32_bf16(bf, afrag[ks], acc[n],
                                                       0, 0, 0);
    }
  }

  // ---- epilogue: lane holds C[bm+w*16+rowc][bn0+n*16+rowg*4 + 0..3] ----
  const long row = bm + w * 16 + rowc;
#pragma unroll
  for (int n = 0; n < 4; ++n) {
    const int col = bn0 + n * 16 + rowg * 4;
    const float4 bb = *(const float4*)(bias + col);
    const float v0 = acc[n][0] + bb.x;
    const float v1 = acc[n][1] + bb.y;
    const float v2 = acc[n][2] + bb.z;
    const float v3 = acc[n][3] + bb.w;
    if constexpr (MODE == 0) {
      float4 s = {v0, v1, v2, v3};
      *(float4*)((float*)Cout + row * n_total + col) = s;
    } else if constexpr (MODE == 1) {
      union { unsigned u[2]; uint2 d; } pk;
      asm("v_cvt_pk_bf16_f32 %0, %1, %2" : "=v"(pk.u[0]) : "v"(v0), "v"(v1));
      asm("v_cvt_pk_bf16_f32 %0, %1, %2" : "=v"(pk.u[1]) : "v"(v2), "v"(v3));
      *(uint2*)((unsigned short*)Cout + row * n_total + col) = pk.d;
    } else {
      if (bn0 < 768) {
        float4 s = {v0, v1, v2, v3};
        *(float4*)((float*)Cout + row * n_total + col) = s;
      } else {
        union { unsigned u[2]; uint2 d; } pk;
        const float r0 = fmaxf(v0, 0.f), r1 = fmaxf(v1, 0.f);
        const float r2 = fmaxf(v2, 0.f), r3 = fmaxf(v3, 0.f);
        asm("v_cvt_pk_bf16_f32 %0, %1, %2" : "=v"(pk.u[0]) : "v"(r0), "v"(r1));
        asm("v_cvt_pk_bf16_f32 %0, %1, %2" : "=v"(pk.u[1]) : "v"(r2), "v"(r3));
        *(uint2*)(aux + row * 128 + (col - 768)) = pk.d;
      }
    }
  }
}

// ---------------------------------------------------------------------------
// Sampling with fused finalize: phase 1 computes softmax + grid + corner
// offsets/weights into LDS; phase 2 gathers v (bf16).
// Block = 2 queries, 256 threads.
// ---------------------------------------------------------------------------
__global__ __launch_bounds__(256) void sample_kernel(
    const unsigned short* __restrict__ v, const float* __restrict__ proj,
    const float* __restrict__ off2, const float* __restrict__ refpts,
    float* __restrict__ acc_out) {
  __shared__ int4 sidx[512];
  __shared__ float4 sw[512];
  const int tid = threadIdx.x;
  const long q0 = (long)blockIdx.x * 2;
  const int b = (int)(q0 >> 11);
  constexpr int starts[4] = {0, 16384, 20480, 21504};

#pragma unroll
  for (int ss = 0; ss < 2; ++ss) {
    const int s = tid + ss * 256;
    const int qq = s >> 8, j = s & 255;       // j = h*32 + l*8 + p
    const long qi = q0 + qq;
    const int l = (j >> 3) & 3;
    const int HW = 128 >> l;
    const float fHW = (float)HW;

    const float logit = proj[qi * 1024 + 512 + j];
    float mx = logit;
#pragma unroll
    for (int mask = 16; mask > 0; mask >>= 1)
      mx = fmaxf(mx, __shfl_xor(mx, mask));
    const float e = __expf(logit - mx);
    float sum = e;
#pragma unroll
    for (int mask = 16; mask > 0; mask >>= 1) sum += __shfl_xor(sum, mask);
    const float wgt = e / sum;

    const float2 po = *(const float2*)(proj + qi * 1024 + 2 * j);
    const float2 o2 = *(const float2*)(off2 + qi * 512 + 2 * j);
    const float2 rp = *(const float2*)(refpts + qi * 8 + l * 2);
    const float rnorm = 1.f / fHW;
    const float gx = (rp.x + (po.x + 0.1f * o2.x) * rnorm) * 2.f - 1.f;
    const float gy = (rp.y + (po.y + 0.1f * o2.y) * rnorm) * 2.f - 1.f;

    const float x = ((gx + 1.f) * fHW - 1.f) * 0.5f;
    const float y = ((gy + 1.f) * fHW - 1.f) * 0.5f;
    const float x0f = floorf(x), y0f = floorf(y);
    const float lx = x - x0f, ly = y - y0f;
    const int ix0 = (int)x0f, iy0 = (int)y0f;
    const int ix1 = ix0 + 1, iy1 = iy0 + 1;
    const float vx0 = (ix0 >= 0 && ix0 < HW) ? 1.f : 0.f;
    const float vx1 = (ix1 >= 0 && ix1 < HW) ? 1.f : 0.f;
    const float vy0 = (iy0 >= 0 && iy0 < HW) ? 1.f : 0.f;
    const float vy1 = (iy1 >= 0 && iy1 < HW) ? 1.f : 0.f;
    const int cx0 = min(max(ix0, 0), HW - 1);
    const int cx1 = min(max(ix1, 0), HW - 1);
    const int cy0 = min(max(iy0, 0), HW - 1);
    const int cy1 = min(max(iy1, 0), HW - 1);
    const int base = starts[l];
    int4 o;  // byte offsets into v (256 ch * 2 B per location)
    o.x = (base + cy0 * HW + cx0) * 512;
    o.y = (base + cy0 * HW + cx1) * 512;
    o.z = (base + cy1 * HW + cx0) * 512;
    o.w = (base + cy1 * HW + cx1) * 512;
    sidx[s] = o;
    float4 wv;
    wv.x = (1.f - lx) * (1.f - ly) * vx0 * vy0 * wgt;
    wv.y = lx * (1.f - ly) * vx1 * vy0 * wgt;
    wv.z = (1.f - lx) * ly * vx0 * vy1 * wgt;
    wv.w = lx * ly * vx1 * vy1 * wgt;
    sw[s] = wv;
  }
  __syncthreads();

  const int qq = tid >> 7, h = (tid >> 4) & 7, dp = tid & 15;
  const char* vb =
      (const char*)v + ((long)b * LV_SZ * 256 + h * 32 + dp * 2) * 2;
  const int sbase = qq * 256 + h * 32;
  float acc0 = 0.f, acc1 = 0.f;
#pragma unroll 8
  for (int j = 0; j < 32; ++j) {
    const int4 o = sidx[sbase + j];
    const float4 w = sw[sbase + j];
    const ushort2 u0 = *(const ushort2*)(vb + o.x);
    const ushort2 u1 = *(const ushort2*)(vb + o.y);
    const ushort2 u2 = *(const ushort2*)(vb + o.z);
    const ushort2 u3 = *(const ushort2*)(vb + o.w);
    acc0 = fmaf(bf2f(u0.x), w.x, acc0);
    acc1 = fmaf(bf2f(u0.y), w.x, acc1);
    acc0 = fmaf(bf2f(u1.x), w.y, acc0);
    acc1 = fmaf(bf2f(u1.y), w.y, acc1);
    acc0 = fmaf(bf2f(u2.x), w.z, acc0);
    acc1 = fmaf(bf2f(u2.y), w.z, acc1);
    acc0 = fmaf(bf2f(u3.x), w.w, acc0);
    acc1 = fmaf(bf2f(u3.y), w.w, acc1);
  }
  float2 res = {acc0, acc1};
  *(float2*)(acc_out + (q0 + qq) * 256 + h * 32 + dp * 2) = res;
}

// ---------------------------------------------------------------------------
extern "C" void kernel_launch(void* const* d_in, const int* in_sizes, int n_in,
                              void* d_out, int out_size, void* d_ws,
                              size_t ws_size, hipStream_t stream) {
  const float* query  = (const float*)d_in[0];
  const float* refpts = (const float*)d_in[1];
  const float* value  = (const float*)d_in[2];
  const float* W_off  = (const float*)d_in[5];
  const float* b_off  = (const float*)d_in[6];
  const float* W_attn = (const float*)d_in[7];
  const float* b_attn = (const float*)d_in[8];
  const float* Wa1    = (const float*)d_in[9];
  const float* ba1    = (const float*)d_in[10];
  const float* Wa2    = (const float*)d_in[11];
  const float* ba2    = (const float*)d_in[12];
  const float* Wv     = (const float*)d_in[13];
  const float* bv     = (const float*)d_in[14];
  const float* Wo     = (const float*)d_in[15];
  const float* bo     = (const float*)d_in[16];
  float* out = (float*)d_out;

  char* ws = (char*)d_ws;
  // layout (total 122,556,416 B):
  unsigned short* v_ws = (unsigned short*)ws;                   // 44,564,480
  float* proj_ws = (float*)(ws + 44564480);                     // 33,554,432
  float* off2_ws = (float*)(ws + 78118912);                     // 16,777,216
  unsigned short* wcat_ws = (unsigned short*)(ws + 78118912);   // aliases off2
  unsigned short* hidb_ws = (unsigned short*)(ws + 94896128);   //  2,097,152
  float* acc_ws  = (float*)(ws + 96993280);                     //  8,388,608
  unsigned short* wtv_ws  = (unsigned short*)(ws + 122159104);  //    131,072
  unsigned short* wto_ws  = (unsigned short*)(ws + 122290176);  //    131,072
  unsigned short* wa2t_ws = (unsigned short*)(ws + 122421248);  //    131,072
  float* bcat_ws = (float*)(ws + 122552320);                    //      4,096

  // 1) all weight preps, one dispatch
  prep_weights<<<1796, 256, 0, stream>>>(Wv, Wo, W_off, W_attn, Wa1, Wa2,
                                         b_off, b_attn, ba1, wtv_ws, wto_ws,
                                         wcat_ws, wa2t_ws, bcat_ws);
  // 2) v = value @ Wv + bv (bf16): NT=4 n-tiles, 680 m-tiles -> 2720 blocks
  gemm_wave<1, 0, 256, 4><<<2720, 512, 0, stream>>>(
      value, wtv_ws, bv, v_ws, nullptr, 256);
  // 3) proj = query @ wcat + bcat: NT=14 (cols 0..895), 64 m-tiles
  gemm_wave<2, 0, 256, 14><<<896, 512, 0, stream>>>(
      query, wcat_ws, bcat_ws, proj_ws, hidb_ws, 1024);
  // 4) off2 = hidb @ Wa2 + ba2: NT=8, 64 m-tiles
  gemm_wave<0, 1, 128, 8><<<512, 512, 0, stream>>>(
      hidb_ws, wa2t_ws, ba2, off2_ws, nullptr, 512);
  // 5) sampling (softmax+grid fused in)
  sample_kernel<<<NQ_SZ / 2, 256, 0, stream>>>(v_ws, proj_ws, off2_ws, refpts,
                                               acc_ws);
  // 6) out = acc @ Wo + bo: NT=4, 64 m-tiles
  gemm_wave<0, 0, 256, 4><<<256, 512, 0, stream>>>(
      acc_ws, wto_ws, bo, out, nullptr, 256);
}

// Round 14
// 122.497 us; speedup vs baseline: 1.1029x; 1.1029x over previous
//
#include <hip/hip_runtime.h>
#include <math.h>

#define B_SZ 4
#define LQ_SZ 2048
#define C_SZ 256
#define NH_SZ 8
#define NL_SZ 4
#define NP_SZ 8
#define HD_SZ 32
#define LV_SZ 21760
#define NQ_SZ (B_SZ * LQ_SZ)   // 8192
#define MV_SZ (B_SZ * LV_SZ)   // 87040

typedef __attribute__((ext_vector_type(8))) short bf16x8;
typedef __attribute__((ext_vector_type(8))) unsigned short ushort8;
typedef __attribute__((ext_vector_type(4))) float f32x4;

__device__ __forceinline__ float bf2f(unsigned short u) {
  union { float f; unsigned v; } x;
  x.v = ((unsigned)u) << 16;
  return x.f;
}
__device__ __forceinline__ unsigned short f2bf(float f) {
  union { float f; unsigned v; } x;
  x.f = f;
  unsigned r = x.v + 0x7fffu + ((x.v >> 16) & 1u);
  return (unsigned short)(r >> 16);
}

// 8x f32 -> bf16x8 via v_cvt_pk_bf16_f32 (RNE, same as f2bf)
__device__ __forceinline__ bf16x8 cvt8(f32x4 a, f32x4 b) {
  union { unsigned u[4]; bf16x8 v; } r;
  asm("v_cvt_pk_bf16_f32 %0, %1, %2" : "=v"(r.u[0]) : "v"(a[0]), "v"(a[1]));
  asm("v_cvt_pk_bf16_f32 %0, %1, %2" : "=v"(r.u[1]) : "v"(a[2]), "v"(a[3]));
  asm("v_cvt_pk_bf16_f32 %0, %1, %2" : "=v"(r.u[2]) : "v"(b[0]), "v"(b[1]));
  asm("v_cvt_pk_bf16_f32 %0, %1, %2" : "=v"(r.u[3]) : "v"(b[2]), "v"(b[3]));
  return r.v;
}

// bank-permute: bijective on 0..7
__device__ __forceinline__ int swz(int x) {
  return ((x & 1) << 2) | ((x >> 1) & 3);
}

// ---------------------------------------------------------------------------
// One-shot weight prep (grid 1796 x 256).
// ---------------------------------------------------------------------------
__global__ void prep_weights(
    const float* __restrict__ Wv, const float* __restrict__ Wo,
    const float* __restrict__ W_off, const float* __restrict__ W_attn,
    const float* __restrict__ Wa1, const float* __restrict__ Wa2,
    const float* __restrict__ b_off, const float* __restrict__ b_attn,
    const float* __restrict__ ba1,
    unsigned short* __restrict__ wtv, unsigned short* __restrict__ wto,
    unsigned short* __restrict__ wcat, unsigned short* __restrict__ wa2t,
    float* __restrict__ bcat) {
  const int bid = blockIdx.x, t = threadIdx.x;
  if (bid < 256) {
    wtv[bid * 256 + t] = f2bf(Wv[t * 256 + bid]);
  } else if (bid < 512) {
    const int n = bid - 256;
    wto[n * 256 + t] = f2bf(Wo[t * 256 + n]);
  } else if (bid < 1536) {
    const int n = bid - 512;
    float v;
    if (n < 512) v = W_off[t * 512 + n];
    else if (n < 768) v = W_attn[t * 256 + (n - 512)];
    else if (n < 896) v = Wa1[t * 128 + (n - 768)];
    else v = 0.f;
    wcat[n * 256 + t] = f2bf(v);
  } else if (bid < 1792) {
    const int idx = (bid - 1536) * 256 + t;     // < 65536
    const int n = idx >> 7, k = idx & 127;
    wa2t[n * 128 + k] = f2bf(Wa2[k * 512 + n]);
  } else {
    const int idx = (bid - 1792) * 256 + t;     // < 1024
    float v;
    if (idx < 512) v = b_off[idx];
    else if (idx < 768) v = b_attn[idx - 512];
    else if (idx < 896) v = ba1[idx - 768];
    else v = 0.f;
    bcat[idx] = v;
  }
}

// ---------------------------------------------------------------------------
// PERSISTENT pipelined value GEMM: v[87040,256]bf16 = A[87040,256]f32 @
// wtv^T + bv.  512 blocks; block: bn0 = (bid&1)*128, m-tiles bid>>1,
// +256, (+512).  B staged in LDS ONCE (one barrier ever).  A is consumed
// through an 8-slot fragment ring with depth-4 prefetch: while chunk ks
// feeds MFMA, chunk ks+4 (same tile for ks<4, next tile for ks>=4) is in
// flight -> HBM streams continuously through the whole kernel.
// All afrag indices compile-time (full unroll) - no scratch.
// ---------------------------------------------------------------------------
__global__ __launch_bounds__(512, 2) void gemm_vpersist(
    const float* __restrict__ A, const unsigned short* __restrict__ Wt,
    const float* __restrict__ bias, unsigned short* __restrict__ Cout) {
  __shared__ unsigned short Bs[128 * 256];  // 64 KB
  const int bid = blockIdx.x;
  const int bn0 = (bid & 1) * 128;
  const int m0 = bid >> 1;                  // 0..255
  const int tid = threadIdx.x;
  const int lane = tid & 63;
  const int w = tid >> 6;
  const int rowc = lane & 15, rowg = lane >> 4;

  // ---- B staging (once) ----
  {
    const int row = tid >> 2, qq = tid & 3;
    const unsigned short* src = Wt + (long)(bn0 + row) * 256;
    char* dstrow = (char*)Bs + row * 512;
    const int sz = swz(row);
#pragma unroll
    for (int i = 0; i < 8; ++i) {
      const int cl = i * 4 + qq;
      ushort8 u = *(const ushort8*)(src + cl * 8);
      *(ushort8*)(dstrow + (cl ^ sz) * 16) = u;
    }
  }

  const long lanoff = (long)(w * 16 + rowc) * 256 + rowg * 8;
  bf16x8 afrag[8];
  // prologue: chunks 0..3 of first tile
  {
    const float* ap = A + (long)m0 * 32768 + lanoff;
#pragma unroll
    for (int ks = 0; ks < 4; ++ks) {
      f32x4 x0 = *(const f32x4*)(ap + ks * 32);
      f32x4 x1 = *(const f32x4*)(ap + ks * 32 + 4);
      afrag[ks] = cvt8(x0, x1);
    }
  }
  __syncthreads();   // B ready (also drains prologue loads - once only)

  for (int mt = m0; mt < 680; mt += 256) {
    const float* apc = A + (long)mt * 32768 + lanoff;
    const float* apn = A + (long)(mt + 256) * 32768 + lanoff;
    const bool has_next = (mt + 256 < 680);

    f32x4 acc[8];
#pragma unroll
    for (int n = 0; n < 8; ++n) acc[n] = (f32x4){0.f, 0.f, 0.f, 0.f};

#pragma unroll
    for (int ks = 0; ks < 8; ++ks) {
      // depth-4 prefetch into the ring
      if constexpr (true) {
        if (ks < 4) {
          f32x4 x0 = *(const f32x4*)(apc + (ks + 4) * 32);
          f32x4 x1 = *(const f32x4*)(apc + (ks + 4) * 32 + 4);
          afrag[(ks + 4) & 7] = cvt8(x0, x1);
        } else if (has_next) {
          f32x4 x0 = *(const f32x4*)(apn + (ks - 4) * 32);
          f32x4 x1 = *(const f32x4*)(apn + (ks - 4) * 32 + 4);
          afrag[(ks - 4) & 7] = cvt8(x0, x1);
        }
      }
#pragma unroll
      for (int n = 0; n < 8; ++n) {
        const int col = n * 16 + rowc;
        const int cs = (ks * 4 + rowg) ^ swz(col);
        bf16x8 bf = *(const bf16x8*)((const char*)Bs + col * 512 + cs * 16);
        acc[n] = __builtin_amdgcn_mfma_f32_16x16x32_bf16(bf, afrag[ks],
                                                         acc[n], 0, 0, 0);
      }
    }

    // epilogue: lane holds C[mt*128+w*16+rowc][bn0+n*16+rowg*4 .. +3]
    const long row = (long)mt * 128 + w * 16 + rowc;
#pragma unroll
    for (int n = 0; n < 8; ++n) {
      const int col = bn0 + n * 16 + rowg * 4;
      const float4 bb = *(const float4*)(bias + col);
      const float v0 = acc[n][0] + bb.x;
      const float v1 = acc[n][1] + bb.y;
      const float v2 = acc[n][2] + bb.z;
      const float v3 = acc[n][3] + bb.w;
      union { unsigned u[2]; uint2 d; } pk;
      asm("v_cvt_pk_bf16_f32 %0, %1, %2" : "=v"(pk.u[0]) : "v"(v0), "v"(v1));
      asm("v_cvt_pk_bf16_f32 %0, %1, %2" : "=v"(pk.u[1]) : "v"(v2), "v"(v3));
      *(uint2*)(Cout + row * 256 + col) = pk.d;
    }
  }
}

// ---------------------------------------------------------------------------
// Front-loaded single-barrier MFMA GEMM (round-12, verified 122.7 config).
// grid = (n_tiles, m_tiles); BN=128.
// MODE: 0 = f32 out, 1 = bf16 out, 2 = proj (bn0<768 f32; else relu bf16
// -> aux[.,128]).
// ---------------------------------------------------------------------------
template <int MODE, int A_BF16, int K_DIM>
__global__ __launch_bounds__(512, 2) void gemm_wave(
    const void* __restrict__ Ain, const unsigned short* __restrict__ Wt,
    const float* __restrict__ bias, void* __restrict__ Cout,
    unsigned short* __restrict__ aux, int n_total) {
  constexpr int KSTEPS = K_DIM / 32;
  constexpr int CHUNKS = K_DIM / 8;           // 16-B chunks per B row
  __shared__ unsigned short Bs[128 * K_DIM];  // 64 KB (K=256) / 32 KB (K=128)
  const int tid = threadIdx.x;
  const int lane = tid & 63;
  const int w = tid >> 6;
  const int rowc = lane & 15, rowg = lane >> 4;
  const int bn0 = blockIdx.x * 128;
  const long bm = (long)blockIdx.y * 128;

  // ---- (a) B staging: 4 threads per row, interleaved chunks ----
  {
    const int row = tid >> 2, qq = tid & 3;
    const unsigned short* src = Wt + (long)(bn0 + row) * K_DIM;
    char* dstrow = (char*)Bs + row * (K_DIM * 2);
    const int sz = swz(row);
#pragma unroll
    for (int i = 0; i < CHUNKS / 4; ++i) {
      const int cl = i * 4 + qq;
      ushort8 u = *(const ushort8*)(src + cl * 8);
      *(ushort8*)(dstrow + (cl ^ sz) * 16) = u;
    }
  }

  // ---- (b) A front-load into fragment registers ----
  bf16x8 afrag[KSTEPS];
  if constexpr (A_BF16) {
    const unsigned short* ap =
        (const unsigned short*)Ain + (bm + w * 16 + rowc) * (long)K_DIM +
        rowg * 8;
#pragma unroll
    for (int ks = 0; ks < KSTEPS; ++ks)
      afrag[ks] = *(const bf16x8*)(ap + ks * 32);
  } else {
    const float* ap =
        (const float*)Ain + (bm + w * 16 + rowc) * (long)K_DIM + rowg * 8;
#pragma unroll
    for (int ks = 0; ks < KSTEPS; ++ks) {
      f32x4 x0 = *(const f32x4*)(ap + ks * 32);
      f32x4 x1 = *(const f32x4*)(ap + ks * 32 + 4);
      afrag[ks] = cvt8(x0, x1);
    }
  }

  f32x4 acc[8];
#pragma unroll
  for (int n = 0; n < 8; ++n) acc[n] = (f32x4){0.f, 0.f, 0.f, 0.f};

  // ---- (c) the only barrier ----
  __syncthreads();

  // ---- (d) MFMA loop, swapped operands ----
#pragma unroll
  for (int ks = 0; ks < KSTEPS; ++ks) {
#pragma unroll
    for (int n = 0; n < 8; ++n) {
      const int col = n * 16 + rowc;
      const int cs = (ks * 4 + rowg) ^ swz(col);
      bf16x8 bf =
          *(const bf16x8*)((const char*)Bs + col * (K_DIM * 2) + cs * 16);
      acc[n] = __builtin_amdgcn_mfma_f32_16x16x32_bf16(bf, afrag[ks], acc[n],
                                                       0, 0, 0);
    }
  }

  // ---- epilogue: lane holds C[bm+w*16+rowc][bn0+n*16+rowg*4 + 0..3] ----
  const long row = bm + w * 16 + rowc;
#pragma unroll
  for (int n = 0; n < 8; ++n) {
    const int col = bn0 + n * 16 + rowg * 4;
    const float4 bb = *(const float4*)(bias + col);
    const float v0 = acc[n][0] + bb.x;
    const float v1 = acc[n][1] + bb.y;
    const float v2 = acc[n][2] + bb.z;
    const float v3 = acc[n][3] + bb.w;
    if constexpr (MODE == 0) {
      float4 s = {v0, v1, v2, v3};
      *(float4*)((float*)Cout + row * n_total + col) = s;
    } else if constexpr (MODE == 1) {
      union { unsigned u[2]; uint2 d; } pk;
      asm("v_cvt_pk_bf16_f32 %0, %1, %2" : "=v"(pk.u[0]) : "v"(v0), "v"(v1));
      asm("v_cvt_pk_bf16_f32 %0, %1, %2" : "=v"(pk.u[1]) : "v"(v2), "v"(v3));
      *(uint2*)((unsigned short*)Cout + row * n_total + col) = pk.d;
    } else {
      if (bn0 < 768) {
        float4 s = {v0, v1, v2, v3};
        *(float4*)((float*)Cout + row * n_total + col) = s;
      } else {
        union { unsigned u[2]; uint2 d; } pk;
        const float r0 = fmaxf(v0, 0.f), r1 = fmaxf(v1, 0.f);
        const float r2 = fmaxf(v2, 0.f), r3 = fmaxf(v3, 0.f);
        asm("v_cvt_pk_bf16_f32 %0, %1, %2" : "=v"(pk.u[0]) : "v"(r0), "v"(r1));
        asm("v_cvt_pk_bf16_f32 %0, %1, %2" : "=v"(pk.u[1]) : "v"(r2), "v"(r3));
        *(uint2*)(aux + row * 128 + (col - 768)) = pk.d;
      }
    }
  }
}

// ---------------------------------------------------------------------------
// Sampling with fused finalize: phase 1 computes softmax + grid + corner
// offsets/weights into LDS; phase 2 gathers v (bf16).
// Block = 2 queries, 256 threads.
// ---------------------------------------------------------------------------
__global__ __launch_bounds__(256) void sample_kernel(
    const unsigned short* __restrict__ v, const float* __restrict__ proj,
    const float* __restrict__ off2, const float* __restrict__ refpts,
    float* __restrict__ acc_out) {
  __shared__ int4 sidx[512];
  __shared__ float4 sw[512];
  const int tid = threadIdx.x;
  const long q0 = (long)blockIdx.x * 2;
  const int b = (int)(q0 >> 11);
  constexpr int starts[4] = {0, 16384, 20480, 21504};

#pragma unroll
  for (int ss = 0; ss < 2; ++ss) {
    const int s = tid + ss * 256;
    const int qq = s >> 8, j = s & 255;       // j = h*32 + l*8 + p
    const long qi = q0 + qq;
    const int l = (j >> 3) & 3;
    const int HW = 128 >> l;
    const float fHW = (float)HW;

    const float logit = proj[qi * 1024 + 512 + j];
    float mx = logit;
#pragma unroll
    for (int mask = 16; mask > 0; mask >>= 1)
      mx = fmaxf(mx, __shfl_xor(mx, mask));
    const float e = __expf(logit - mx);
    float sum = e;
#pragma unroll
    for (int mask = 16; mask > 0; mask >>= 1) sum += __shfl_xor(sum, mask);
    const float wgt = e / sum;

    const float2 po = *(const float2*)(proj + qi * 1024 + 2 * j);
    const float2 o2 = *(const float2*)(off2 + qi * 512 + 2 * j);
    const float2 rp = *(const float2*)(refpts + qi * 8 + l * 2);
    const float rnorm = 1.f / fHW;
    const float gx = (rp.x + (po.x + 0.1f * o2.x) * rnorm) * 2.f - 1.f;
    const float gy = (rp.y + (po.y + 0.1f * o2.y) * rnorm) * 2.f - 1.f;

    const float x = ((gx + 1.f) * fHW - 1.f) * 0.5f;
    const float y = ((gy + 1.f) * fHW - 1.f) * 0.5f;
    const float x0f = floorf(x), y0f = floorf(y);
    const float lx = x - x0f, ly = y - y0f;
    const int ix0 = (int)x0f, iy0 = (int)y0f;
    const int ix1 = ix0 + 1, iy1 = iy0 + 1;
    const float vx0 = (ix0 >= 0 && ix0 < HW) ? 1.f : 0.f;
    const float vx1 = (ix1 >= 0 && ix1 < HW) ? 1.f : 0.f;
    const float vy0 = (iy0 >= 0 && iy0 < HW) ? 1.f : 0.f;
    const float vy1 = (iy1 >= 0 && iy1 < HW) ? 1.f : 0.f;
    const int cx0 = min(max(ix0, 0), HW - 1);
    const int cx1 = min(max(ix1, 0), HW - 1);
    const int cy0 = min(max(iy0, 0), HW - 1);
    const int cy1 = min(max(iy1, 0), HW - 1);
    const int base = starts[l];
    int4 o;  // byte offsets into v (256 ch * 2 B per location)
    o.x = (base + cy0 * HW + cx0) * 512;
    o.y = (base + cy0 * HW + cx1) * 512;
    o.z = (base + cy1 * HW + cx0) * 512;
    o.w = (base + cy1 * HW + cx1) * 512;
    sidx[s] = o;
    float4 wv;
    wv.x = (1.f - lx) * (1.f - ly) * vx0 * vy0 * wgt;
    wv.y = lx * (1.f - ly) * vx1 * vy0 * wgt;
    wv.z = (1.f - lx) * ly * vx0 * vy1 * wgt;
    wv.w = lx * ly * vx1 * vy1 * wgt;
    sw[s] = wv;
  }
  __syncthreads();

  const int qq = tid >> 7, h = (tid >> 4) & 7, dp = tid & 15;
  const char* vb =
      (const char*)v + ((long)b * LV_SZ * 256 + h * 32 + dp * 2) * 2;
  const int sbase = qq * 256 + h * 32;
  float acc0 = 0.f, acc1 = 0.f;
#pragma unroll 8
  for (int j = 0; j < 32; ++j) {
    const int4 o = sidx[sbase + j];
    const float4 w = sw[sbase + j];
    const ushort2 u0 = *(const ushort2*)(vb + o.x);
    const ushort2 u1 = *(const ushort2*)(vb + o.y);
    const ushort2 u2 = *(const ushort2*)(vb + o.z);
    const ushort2 u3 = *(const ushort2*)(vb + o.w);
    acc0 = fmaf(bf2f(u0.x), w.x, acc0);
    acc1 = fmaf(bf2f(u0.y), w.x, acc1);
    acc0 = fmaf(bf2f(u1.x), w.y, acc0);
    acc1 = fmaf(bf2f(u1.y), w.y, acc1);
    acc0 = fmaf(bf2f(u2.x), w.z, acc0);
    acc1 = fmaf(bf2f(u2.y), w.z, acc1);
    acc0 = fmaf(bf2f(u3.x), w.w, acc0);
    acc1 = fmaf(bf2f(u3.y), w.w, acc1);
  }
  float2 res = {acc0, acc1};
  *(float2*)(acc_out + (q0 + qq) * 256 + h * 32 + dp * 2) = res;
}

// ---------------------------------------------------------------------------
extern "C" void kernel_launch(void* const* d_in, const int* in_sizes, int n_in,
                              void* d_out, int out_size, void* d_ws,
                              size_t ws_size, hipStream_t stream) {
  const float* query  = (const float*)d_in[0];
  const float* refpts = (const float*)d_in[1];
  const float* value  = (const float*)d_in[2];
  const float* W_off  = (const float*)d_in[5];
  const float* b_off  = (const float*)d_in[6];
  const float* W_attn = (const float*)d_in[7];
  const float* b_attn = (const float*)d_in[8];
  const float* Wa1    = (const float*)d_in[9];
  const float* ba1    = (const float*)d_in[10];
  const float* Wa2    = (const float*)d_in[11];
  const float* ba2    = (const float*)d_in[12];
  const float* Wv     = (const float*)d_in[13];
  const float* bv     = (const float*)d_in[14];
  const float* Wo     = (const float*)d_in[15];
  const float* bo     = (const float*)d_in[16];
  float* out = (float*)d_out;

  char* ws = (char*)d_ws;
  // layout (total 122,556,416 B):
  unsigned short* v_ws = (unsigned short*)ws;                   // 44,564,480
  float* proj_ws = (float*)(ws + 44564480);                     // 33,554,432
  float* off2_ws = (float*)(ws + 78118912);                     // 16,777,216
  unsigned short* wcat_ws = (unsigned short*)(ws + 78118912);   // aliases off2
  unsigned short* hidb_ws = (unsigned short*)(ws + 94896128);   //  2,097,152
  float* acc_ws  = (float*)(ws + 96993280);                     //  8,388,608
  unsigned short* wtv_ws  = (unsigned short*)(ws + 122159104);  //    131,072
  unsigned short* wto_ws  = (unsigned short*)(ws + 122290176);  //    131,072
  unsigned short* wa2t_ws = (unsigned short*)(ws + 122421248);  //    131,072
  float* bcat_ws = (float*)(ws + 122552320);                    //      4,096

  // 1) all weight preps, one dispatch
  prep_weights<<<1796, 256, 0, stream>>>(Wv, Wo, W_off, W_attn, Wa1, Wa2,
                                         b_off, b_attn, ba1, wtv_ws, wto_ws,
                                         wcat_ws, wa2t_ws, bcat_ws);
  // 2) v = value @ Wv + bv (bf16): persistent pipelined, 512 blocks
  gemm_vpersist<<<512, 512, 0, stream>>>(value, wtv_ws, bv, v_ws);
  // 3) proj = query @ wcat + bcat (bn0<768 f32; bn0==768 tile relu->hidb)
  gemm_wave<2, 0, 256><<<dim3(7, NQ_SZ / 128), 512, 0, stream>>>(
      query, wcat_ws, bcat_ws, proj_ws, hidb_ws, 1024);
  // 4) off2 = hidb @ Wa2 + ba2
  gemm_wave<0, 1, 128><<<dim3(4, NQ_SZ / 128), 512, 0, stream>>>(
      hidb_ws, wa2t_ws, ba2, off2_ws, nullptr, 512);
  // 5) sampling (softmax+grid fused in)
  sample_kernel<<<NQ_SZ / 2, 256, 0, stream>>>(v_ws, proj_ws, off2_ws, refpts,
                                               acc_ws);
  // 6) out = acc @ Wo + bo
  gemm_wave<0, 0, 256><<<dim3(2, NQ_SZ / 128), 512, 0, stream>>>(
      acc_ws, wto_ws, bo, out, nullptr, 256);
}